// Round 4
// baseline (636.219 us; speedup 1.0000x reference)
//
#include <hip/hip_runtime.h>
#include <hip/hip_bf16.h>
#include <math.h>

#define DIM 768

typedef __bf16 bf16_t;
typedef __attribute__((ext_vector_type(8))) __bf16 bf16x8;
typedef __attribute__((ext_vector_type(4))) float f32x4;

#define GLOAD_LDS16(g, l)                                                  \
    __builtin_amdgcn_global_load_lds(                                      \
        (const __attribute__((address_space(1))) void*)(g),                \
        (__attribute__((address_space(3))) void*)(l), 16, 0, 0)

__device__ __forceinline__ float bf2f(unsigned short u) {
    union { unsigned int i; float f; } x;
    x.i = ((unsigned int)u) << 16;
    return x.f;
}

// ---------------------------------------------------------------------------
// CSR build
// ---------------------------------------------------------------------------
__global__ __launch_bounds__(256) void hist_kernel(const int* __restrict__ dst,
                                                   int* __restrict__ deg, int E) {
    int e = blockIdx.x * 256 + threadIdx.x;
    if (e < E) atomicAdd(&deg[dst[e]], 1);
}

__global__ __launch_bounds__(1024) void scan_kernel(const int* __restrict__ deg,
                                                    int* __restrict__ row_start,
                                                    int* __restrict__ cursor, int n) {
    __shared__ int sh[1024];
    __shared__ int carry_sh;
    int tid = threadIdx.x;
    if (tid == 0) carry_sh = 0;
    __syncthreads();
    for (int base = 0; base < n; base += 1024) {
        int i = base + tid;
        int v = (i < n) ? deg[i] : 0;
        sh[tid] = v;
        __syncthreads();
        for (int off = 1; off < 1024; off <<= 1) {
            int t = (tid >= off) ? sh[tid - off] : 0;
            __syncthreads();
            sh[tid] += t;
            __syncthreads();
        }
        int incl = sh[tid];
        int carry = carry_sh;
        int excl = carry + incl - v;
        if (i < n) { row_start[i] = excl; cursor[i] = excl; }
        __syncthreads();
        if (tid == 1023) carry_sh = carry + incl;
        __syncthreads();
    }
    if (tid == 0) row_start[n] = carry_sh;
}

__global__ __launch_bounds__(256) void scatter_kernel(const int* __restrict__ src,
                                                      const int* __restrict__ dst,
                                                      int* __restrict__ cursor,
                                                      int* __restrict__ csr_src, int E) {
    int e = blockIdx.x * 256 + threadIdx.x;
    if (e < E) {
        int p = atomicAdd(&cursor[dst[e]], 1);
        csr_src[p] = src[e];
    }
}

// ---------------------------------------------------------------------------
// fp32 -> bf16 elementwise convert (8 elems/thread)
// ---------------------------------------------------------------------------
__global__ __launch_bounds__(256) void conv_bf16_kernel(const float* __restrict__ in,
                                                        __hip_bfloat16* __restrict__ out,
                                                        int n8) {
    int i = blockIdx.x * 256 + threadIdx.x;
    if (i >= n8) return;
    const float4* p = reinterpret_cast<const float4*>(in + (size_t)i * 8);
    float4 a = p[0], b = p[1];
    __hip_bfloat16 v[8];
    v[0] = __float2bfloat16(a.x); v[1] = __float2bfloat16(a.y);
    v[2] = __float2bfloat16(a.z); v[3] = __float2bfloat16(a.w);
    v[4] = __float2bfloat16(b.x); v[5] = __float2bfloat16(b.y);
    v[6] = __float2bfloat16(b.z); v[7] = __float2bfloat16(b.w);
    *reinterpret_cast<uint4*>(out + (size_t)i * 8) = *reinterpret_cast<uint4*>(v);
}

// ---------------------------------------------------------------------------
// W [K][Nc] f32  ->  Wt [Nc][K] bf16  (tiled transpose)
// ---------------------------------------------------------------------------
__global__ __launch_bounds__(256) void transpose_bf16_kernel(const float* __restrict__ W,
                                                             __hip_bfloat16* __restrict__ Wt,
                                                             int K, int Nc) {
    __shared__ float tile[32][33];
    int bk = blockIdx.x * 32, bn = blockIdx.y * 32;
    int tx = threadIdx.x & 31, ty = threadIdx.x >> 5;  // 32 x 8
#pragma unroll
    for (int r = ty; r < 32; r += 8)
        tile[r][tx] = W[(size_t)(bk + r) * Nc + bn + tx];
    __syncthreads();
#pragma unroll
    for (int r = ty; r < 32; r += 8)
        Wt[(size_t)(bn + r) * K + bk + tx] = __float2bfloat16(tile[tx][r]);
}

// ---------------------------------------------------------------------------
// Dual bf16 MFMA GEMM, 1D grid with bijective XCD-chunk swizzle (T1/m204),
// bn-fastest ordering so the 12 consumers of each A-panel are XCD-local.
// ---------------------------------------------------------------------------
__global__ __launch_bounds__(256) void gemm_mfma_dual_kernel(
    const bf16_t* __restrict__ Xb,   // [M][768]
    const bf16_t* __restrict__ Wt,   // [1536][768]
    const float* __restrict__ b1, const float* __restrict__ b2,
    __hip_bfloat16* __restrict__ C1, __hip_bfloat16* __restrict__ C2, int M) {
    __shared__ __align__(16) bf16_t As[128 * 64];
    __shared__ __align__(16) bf16_t Bs[128 * 64];

    // bijective XCD swizzle (nwg need not be %8): chunk per XCD, bn fastest
    const int nwg = gridDim.x;
    const int o = blockIdx.x;
    const int q = nwg >> 3, r = nwg & 7;
    const int xcd = o & 7, jj = o >> 3;
    const int lin = (xcd < r ? xcd * (q + 1) : r * (q + 1) + (xcd - r) * q) + jj;
    const int bn = (lin % 12) * 128;   // 1536/128 = 12 N-tiles
    const int bm = (lin / 12) * 128;

    const int tid = threadIdx.x;
    const int lane = tid & 63;
    const int w = tid >> 6;
    const int wr = w >> 1, wc = w & 1;

    f32x4 acc[4][4];
    {
        const float* bp = (bn < DIM) ? b1 : b2;
        int cb = (bn < DIM) ? bn : bn - DIM;
#pragma unroll
        for (int ni = 0; ni < 4; ++ni) {
            float bv = bp[cb + wc * 64 + ni * 16 + (lane & 15)];
#pragma unroll
            for (int mi = 0; mi < 4; ++mi) acc[mi][ni] = f32x4{bv, bv, bv, bv};
        }
    }

    const int srow = w * 32 + (lane >> 3);
    const int scol = (lane & 7) * 8;

    for (int k0 = 0; k0 < DIM; k0 += 64) {
#pragma unroll
        for (int i = 0; i < 4; ++i) {
            int rr = srow + i * 8;
            int col = scol ^ ((rr & 7) << 3);
            int rg = bm + rr; rg = rg < M ? rg : M - 1;
            GLOAD_LDS16(Xb + (size_t)rg * DIM + k0 + col, &As[(w * 32 + i * 8) * 64]);
        }
#pragma unroll
        for (int i = 0; i < 4; ++i) {
            int rr = srow + i * 8;
            int col = scol ^ ((rr & 7) << 3);
            GLOAD_LDS16(Wt + (size_t)(bn + rr) * DIM + k0 + col, &Bs[(w * 32 + i * 8) * 64]);
        }
        __syncthreads();

#pragma unroll
        for (int kk = 0; kk < 2; ++kk) {
            bf16x8 af[4], bfr[4];
            int ke = kk * 32 + (lane >> 4) * 8;
#pragma unroll
            for (int mi = 0; mi < 4; ++mi) {
                int rr = wr * 64 + mi * 16 + (lane & 15);
                af[mi] = *(const bf16x8*)&As[rr * 64 + (ke ^ ((rr & 7) << 3))];
            }
#pragma unroll
            for (int ni = 0; ni < 4; ++ni) {
                int rr = wc * 64 + ni * 16 + (lane & 15);
                bfr[ni] = *(const bf16x8*)&Bs[rr * 64 + (ke ^ ((rr & 7) << 3))];
            }
#pragma unroll
            for (int mi = 0; mi < 4; ++mi)
#pragma unroll
                for (int ni = 0; ni < 4; ++ni)
                    acc[mi][ni] = __builtin_amdgcn_mfma_f32_16x16x32_bf16(
                        af[mi], bfr[ni], acc[mi][ni], 0, 0, 0);
        }
        __syncthreads();
    }

    __hip_bfloat16* C = (bn < DIM) ? C1 : C2;
    int cb = (bn < DIM) ? bn : bn - DIM;
#pragma unroll
    for (int mi = 0; mi < 4; ++mi) {
#pragma unroll
        for (int j = 0; j < 4; ++j) {
            int row = bm + wr * 64 + mi * 16 + (lane >> 4) * 4 + j;
            if (row < M) {
#pragma unroll
                for (int ni = 0; ni < 4; ++ni) {
                    int col = cb + wc * 64 + ni * 16 + (lane & 15);
                    C[(size_t)row * DIM + col] = __float2bfloat16(acc[mi][ni][j]);
                }
            }
        }
    }
}

// ---------------------------------------------------------------------------
// Per-node GAT: one wave per dst node, online softmax with defer-max (T13,
// THR=8) + 2-buffer edge prefetch. fs/fd bf16.
// ---------------------------------------------------------------------------
__device__ __forceinline__ void load12(const unsigned short* __restrict__ p, float* v) {
    ushort4 a = *reinterpret_cast<const ushort4*>(p);
    ushort4 b = *reinterpret_cast<const ushort4*>(p + 4);
    ushort4 c = *reinterpret_cast<const ushort4*>(p + 8);
    v[0] = bf2f(a.x); v[1] = bf2f(a.y); v[2] = bf2f(a.z); v[3] = bf2f(a.w);
    v[4] = bf2f(b.x); v[5] = bf2f(b.y); v[6] = bf2f(b.z); v[7] = bf2f(b.w);
    v[8] = bf2f(c.x); v[9] = bf2f(c.y); v[10] = bf2f(c.z); v[11] = bf2f(c.w);
}

// one edge: logit -> group reduce -> defer-max online softmax update
#define PROCESS(FV)                                                         \
    do {                                                                    \
        float t = 0.f;                                                      \
        _Pragma("unroll") for (int j = 0; j < 12; ++j) {                    \
            float u = FV[j] + fdv[j];                                       \
            u = fmaxf(u, 0.2f * u);                                         \
            t = fmaf(u, av[j], t);                                          \
        }                                                                   \
        _Pragma("unroll") for (int off = 1; off < G; off <<= 1)             \
            t += __shfl_xor(t, off, 64);                                    \
        if (__builtin_expect(!__all(t <= m + 8.f), 0)) {                    \
            float mn = fmaxf(m, t);                                         \
            float c = __expf(m - mn);                                       \
            float ex = __expf(t - mn);                                      \
            denom = denom * c + ex;                                         \
            _Pragma("unroll") for (int j = 0; j < 12; ++j)                  \
                agg[j] = fmaf(agg[j], c, ex * FV[j]);                       \
            m = mn;                                                         \
        } else {                                                            \
            float ex = __expf(t - m);                                       \
            denom += ex;                                                    \
            _Pragma("unroll") for (int j = 0; j < 12; ++j)                  \
                agg[j] = fmaf(ex, FV[j], agg[j]);                           \
        }                                                                   \
    } while (0)

template <int H>
__global__ __launch_bounds__(256, 6) void gat_node_kernel(
    const unsigned short* __restrict__ fs, const unsigned short* __restrict__ fd,
    const int* __restrict__ row_start, const int* __restrict__ csr_src,
    const float* __restrict__ attn, const float* __restrict__ resid,
    const float* __restrict__ ln_w, const float* __restrict__ ln_b,
    float* __restrict__ outf, __hip_bfloat16* __restrict__ outb, int n_nodes) {
    constexpr int G = 64 / H;
    int wave = threadIdx.x >> 6;
    int lane = threadIdx.x & 63;
    int node = blockIdx.x * 4 + wave;
    if (node >= n_nodes) return;
    int d0 = lane * 12;

    float fdv[12], av[12], agg[12];
    load12(fd + (size_t)node * DIM + d0, fdv);
    {
        const float4* p = reinterpret_cast<const float4*>(attn + d0);
        float4 q0 = p[0], q1 = p[1], q2 = p[2];
        av[0] = q0.x; av[1] = q0.y; av[2] = q0.z; av[3] = q0.w;
        av[4] = q1.x; av[5] = q1.y; av[6] = q1.z; av[7] = q1.w;
        av[8] = q2.x; av[9] = q2.y; av[10] = q2.z; av[11] = q2.w;
    }
#pragma unroll
    for (int j = 0; j < 12; ++j) agg[j] = 0.f;

    int p0 = row_start[node], p1 = row_start[node + 1];
    int np = p1 - p0;
    float m = -INFINITY;
    float denom = 0.f;

    const unsigned short* fsl = fs + d0;
    const int* ip = csr_src + p0;

    float fvA[12], fvB[12];
    if (np > 0) load12(fsl + (size_t)ip[0] * DIM, fvA);
    if (np > 1) load12(fsl + (size_t)ip[1] * DIM, fvB);

    int i = 0;
    for (; i + 2 <= np; i += 2) {
        PROCESS(fvA);
        if (i + 2 < np) load12(fsl + (size_t)ip[i + 2] * DIM, fvA);
        PROCESS(fvB);
        if (i + 3 < np) load12(fsl + (size_t)ip[i + 3] * DIM, fvB);
    }
    if (i < np) PROCESS(fvA);

    float inv = (denom > 0.f) ? 1.0f / denom : 0.f;
    float vals[12];
#pragma unroll
    for (int j = 0; j < 12; ++j) {
        float v = agg[j] * inv;
        vals[j] = (v > 0.f) ? v : expm1f(v);
    }
    if (resid != nullptr) {
        const float4* p = reinterpret_cast<const float4*>(resid + (size_t)node * DIM + d0);
        float4 q0 = p[0], q1 = p[1], q2 = p[2];
        vals[0] += q0.x; vals[1] += q0.y; vals[2] += q0.z; vals[3] += q0.w;
        vals[4] += q1.x; vals[5] += q1.y; vals[6] += q1.z; vals[7] += q1.w;
        vals[8] += q2.x; vals[9] += q2.y; vals[10] += q2.z; vals[11] += q2.w;
    }
    float s1 = 0.f;
#pragma unroll
    for (int j = 0; j < 12; ++j) s1 += vals[j];
#pragma unroll
    for (int off = 1; off < 64; off <<= 1) s1 += __shfl_xor(s1, off, 64);
    float mu = s1 * (1.0f / DIM);
    float s2 = 0.f;
#pragma unroll
    for (int j = 0; j < 12; ++j) {
        float dlt = vals[j] - mu;
        s2 = fmaf(dlt, dlt, s2);
    }
#pragma unroll
    for (int off = 1; off < 64; off <<= 1) s2 += __shfl_xor(s2, off, 64);
    float rs = rsqrtf(s2 * (1.0f / DIM) + 1e-5f);

    float wv[12], bv[12];
    {
        const float4* p = reinterpret_cast<const float4*>(ln_w + d0);
        float4 q0 = p[0], q1 = p[1], q2 = p[2];
        wv[0] = q0.x; wv[1] = q0.y; wv[2] = q0.z; wv[3] = q0.w;
        wv[4] = q1.x; wv[5] = q1.y; wv[6] = q1.z; wv[7] = q1.w;
        wv[8] = q2.x; wv[9] = q2.y; wv[10] = q2.z; wv[11] = q2.w;
        const float4* pb = reinterpret_cast<const float4*>(ln_b + d0);
        float4 r0 = pb[0], r1 = pb[1], r2 = pb[2];
        bv[0] = r0.x; bv[1] = r0.y; bv[2] = r0.z; bv[3] = r0.w;
        bv[4] = r1.x; bv[5] = r1.y; bv[6] = r1.z; bv[7] = r1.w;
        bv[8] = r2.x; bv[9] = r2.y; bv[10] = r2.z; bv[11] = r2.w;
    }
    float o[12];
#pragma unroll
    for (int j = 0; j < 12; ++j)
        o[j] = (vals[j] - mu) * rs * wv[j] + bv[j];

    if (outf != nullptr) {
        float* op = outf + (size_t)node * DIM + d0;
#pragma unroll
        for (int qq = 0; qq < 3; ++qq) {
            float4 t4 = make_float4(o[qq * 4 + 0], o[qq * 4 + 1], o[qq * 4 + 2], o[qq * 4 + 3]);
            *reinterpret_cast<float4*>(op + qq * 4) = t4;
        }
    }
    if (outb != nullptr) {
        __hip_bfloat16 hb[12];
#pragma unroll
        for (int j = 0; j < 12; ++j) hb[j] = __float2bfloat16(o[j]);
        unsigned short* op = (unsigned short*)outb + (size_t)node * DIM + d0;
#pragma unroll
        for (int qq = 0; qq < 3; ++qq)
            *reinterpret_cast<ushort4*>(op + qq * 4) =
                *reinterpret_cast<ushort4*>(&hb[qq * 4]);
    }
}

// ---------------------------------------------------------------------------
extern "C" void kernel_launch(void* const* d_in, const int* in_sizes, int n_in,
                              void* d_out, int out_size, void* d_ws, size_t ws_size,
                              hipStream_t stream) {
    const float* x     = (const float*)d_in[0];
    const int*   src   = (const int*)d_in[1];
    const int*   dst   = (const int*)d_in[2];
    const float* W1s   = (const float*)d_in[3];
    const float* b1s   = (const float*)d_in[4];
    const float* W1d   = (const float*)d_in[5];
    const float* b1d   = (const float*)d_in[6];
    const float* attn1 = (const float*)d_in[7];
    const float* ln1w  = (const float*)d_in[8];
    const float* ln1b  = (const float*)d_in[9];
    const float* Wos   = (const float*)d_in[10];
    const float* bos   = (const float*)d_in[11];
    const float* Wod   = (const float*)d_in[12];
    const float* bod   = (const float*)d_in[13];
    const float* attno = (const float*)d_in[14];
    const float* lnow  = (const float*)d_in[15];
    const float* lnob  = (const float*)d_in[16];
    float* out = (float*)d_out;

    const int N = in_sizes[0] / DIM;   // 20000
    const int E = in_sizes[1];         // 320000

    __hip_bfloat16* fsb = (__hip_bfloat16*)d_ws;
    __hip_bfloat16* fdb = fsb + (size_t)N * DIM;
    __hip_bfloat16* Xb  = fdb + (size_t)N * DIM;
    __hip_bfloat16* W1t = Xb + (size_t)N * DIM;
    __hip_bfloat16* Wot = W1t + (size_t)2 * DIM * DIM;
    int* csr_src   = (int*)(Wot + (size_t)2 * DIM * DIM);
    int* row_start = csr_src + E;
    int* cursor    = row_start + (N + 1);
    int* deg       = cursor + N;

    // --- CSR by dst (shared by both layers)
    hipMemsetAsync(deg, 0, (size_t)N * sizeof(int), stream);
    hist_kernel<<<(E + 255) / 256, 256, 0, stream>>>(dst, deg, E);
    scan_kernel<<<1, 1024, 0, stream>>>(deg, row_start, cursor, N);
    scatter_kernel<<<(E + 255) / 256, 256, 0, stream>>>(src, dst, cursor, csr_src, E);

    // --- weight transposes (f32 -> bf16, [K][N] -> [N][K])
    dim3 tg(DIM / 32, DIM / 32);
    transpose_bf16_kernel<<<tg, 256, 0, stream>>>(W1s, W1t, DIM, DIM);
    transpose_bf16_kernel<<<tg, 256, 0, stream>>>(W1d, W1t + (size_t)DIM * DIM, DIM, DIM);
    transpose_bf16_kernel<<<tg, 256, 0, stream>>>(Wos, Wot, DIM, DIM);
    transpose_bf16_kernel<<<tg, 256, 0, stream>>>(Wod, Wot + (size_t)DIM * DIM, DIM, DIM);

    const int n8 = N * DIM / 8;
    const int mt = (N + 127) / 128;
    const int nwg = mt * 12;  // 1D swizzled grid

    // --- layer 1: GEMM -> gat (writes bf16 h straight into Xb for layer 2)
    conv_bf16_kernel<<<(n8 + 255) / 256, 256, 0, stream>>>(x, Xb, n8);
    gemm_mfma_dual_kernel<<<nwg, 256, 0, stream>>>(
        (const bf16_t*)Xb, (const bf16_t*)W1t, b1s, b1d, fsb, fdb, N);
    gat_node_kernel<8><<<(N + 3) / 4, 256, 0, stream>>>(
        (const unsigned short*)fsb, (const unsigned short*)fdb, row_start, csr_src,
        attn1, x, ln1w, ln1b, nullptr, Xb, N);

    // --- layer 2: GEMM -> gat -> final f32 out
    gemm_mfma_dual_kernel<<<nwg, 256, 0, stream>>>(
        (const bf16_t*)Xb, (const bf16_t*)Wot, bos, bod, fsb, fdb, N);
    gat_node_kernel<1><<<(N + 3) / 4, 256, 0, stream>>>(
        (const unsigned short*)fsb, (const unsigned short*)fdb, row_start, csr_src,
        attno, nullptr, lnow, lnob, out, nullptr, N);
}

// Round 5
// 451.342 us; speedup vs baseline: 1.4096x; 1.4096x over previous
//
#include <hip/hip_runtime.h>
#include <hip/hip_bf16.h>
#include <math.h>

#define DIM 768

typedef __bf16 bf16_t;
typedef __attribute__((ext_vector_type(8))) __bf16 bf16x8;
typedef __attribute__((ext_vector_type(4))) float f32x4;

#define GLOAD_LDS16(g, l)                                                  \
    __builtin_amdgcn_global_load_lds(                                      \
        (const __attribute__((address_space(1))) void*)(g),                \
        (__attribute__((address_space(3))) void*)(l), 16, 0, 0)

__device__ __forceinline__ float bf2f(unsigned short u) {
    union { unsigned int i; float f; } x;
    x.i = ((unsigned int)u) << 16;
    return x.f;
}

// ---------------------------------------------------------------------------
// CSR build
// ---------------------------------------------------------------------------
__global__ __launch_bounds__(256) void hist_kernel(const int* __restrict__ dst,
                                                   int* __restrict__ deg, int E) {
    int e = blockIdx.x * 256 + threadIdx.x;
    if (e < E) atomicAdd(&deg[dst[e]], 1);
}

__global__ __launch_bounds__(1024) void scan_kernel(const int* __restrict__ deg,
                                                    int* __restrict__ row_start,
                                                    int* __restrict__ cursor, int n) {
    __shared__ int sh[1024];
    __shared__ int carry_sh;
    int tid = threadIdx.x;
    if (tid == 0) carry_sh = 0;
    __syncthreads();
    for (int base = 0; base < n; base += 1024) {
        int i = base + tid;
        int v = (i < n) ? deg[i] : 0;
        sh[tid] = v;
        __syncthreads();
        for (int off = 1; off < 1024; off <<= 1) {
            int t = (tid >= off) ? sh[tid - off] : 0;
            __syncthreads();
            sh[tid] += t;
            __syncthreads();
        }
        int incl = sh[tid];
        int carry = carry_sh;
        int excl = carry + incl - v;
        if (i < n) { row_start[i] = excl; cursor[i] = excl; }
        __syncthreads();
        if (tid == 1023) carry_sh = carry + incl;
        __syncthreads();
    }
    if (tid == 0) row_start[n] = carry_sh;
}

__global__ __launch_bounds__(256) void scatter_kernel(const int* __restrict__ src,
                                                      const int* __restrict__ dst,
                                                      int* __restrict__ cursor,
                                                      int* __restrict__ csr_src, int E) {
    int e = blockIdx.x * 256 + threadIdx.x;
    if (e < E) {
        int p = atomicAdd(&cursor[dst[e]], 1);
        csr_src[p] = src[e];
    }
}

// ---------------------------------------------------------------------------
// fp32 -> bf16 elementwise convert (8 elems/thread)
// ---------------------------------------------------------------------------
__global__ __launch_bounds__(256) void conv_bf16_kernel(const float* __restrict__ in,
                                                        __hip_bfloat16* __restrict__ out,
                                                        int n8) {
    int i = blockIdx.x * 256 + threadIdx.x;
    if (i >= n8) return;
    const float4* p = reinterpret_cast<const float4*>(in + (size_t)i * 8);
    float4 a = p[0], b = p[1];
    __hip_bfloat16 v[8];
    v[0] = __float2bfloat16(a.x); v[1] = __float2bfloat16(a.y);
    v[2] = __float2bfloat16(a.z); v[3] = __float2bfloat16(a.w);
    v[4] = __float2bfloat16(b.x); v[5] = __float2bfloat16(b.y);
    v[6] = __float2bfloat16(b.z); v[7] = __float2bfloat16(b.w);
    *reinterpret_cast<uint4*>(out + (size_t)i * 8) = *reinterpret_cast<uint4*>(v);
}

// ---------------------------------------------------------------------------
// W [K][Nc] f32  ->  Wt [Nc][K] bf16  (tiled transpose)
// ---------------------------------------------------------------------------
__global__ __launch_bounds__(256) void transpose_bf16_kernel(const float* __restrict__ W,
                                                             __hip_bfloat16* __restrict__ Wt,
                                                             int K, int Nc) {
    __shared__ float tile[32][33];
    int bk = blockIdx.x * 32, bn = blockIdx.y * 32;
    int tx = threadIdx.x & 31, ty = threadIdx.x >> 5;  // 32 x 8
#pragma unroll
    for (int r = ty; r < 32; r += 8)
        tile[r][tx] = W[(size_t)(bk + r) * Nc + bn + tx];
    __syncthreads();
#pragma unroll
    for (int r = ty; r < 32; r += 8)
        Wt[(size_t)(bn + r) * K + bk + tx] = __float2bfloat16(tile[tx][r]);
}

// ---------------------------------------------------------------------------
// Dual bf16 MFMA GEMM, 1D grid with bijective XCD-chunk swizzle (T1/m204)
// ---------------------------------------------------------------------------
__global__ __launch_bounds__(256) void gemm_mfma_dual_kernel(
    const bf16_t* __restrict__ Xb,   // [M][768]
    const bf16_t* __restrict__ Wt,   // [1536][768]
    const float* __restrict__ b1, const float* __restrict__ b2,
    __hip_bfloat16* __restrict__ C1, __hip_bfloat16* __restrict__ C2, int M) {
    __shared__ __align__(16) bf16_t As[128 * 64];
    __shared__ __align__(16) bf16_t Bs[128 * 64];

    const int nwg = gridDim.x;
    const int o = blockIdx.x;
    const int q = nwg >> 3, r = nwg & 7;
    const int xcd = o & 7, jj = o >> 3;
    const int lin = (xcd < r ? xcd * (q + 1) : r * (q + 1) + (xcd - r) * q) + jj;
    const int bn = (lin % 12) * 128;
    const int bm = (lin / 12) * 128;

    const int tid = threadIdx.x;
    const int lane = tid & 63;
    const int w = tid >> 6;
    const int wr = w >> 1, wc = w & 1;

    f32x4 acc[4][4];
    {
        const float* bp = (bn < DIM) ? b1 : b2;
        int cb = (bn < DIM) ? bn : bn - DIM;
#pragma unroll
        for (int ni = 0; ni < 4; ++ni) {
            float bv = bp[cb + wc * 64 + ni * 16 + (lane & 15)];
#pragma unroll
            for (int mi = 0; mi < 4; ++mi) acc[mi][ni] = f32x4{bv, bv, bv, bv};
        }
    }

    const int srow = w * 32 + (lane >> 3);
    const int scol = (lane & 7) * 8;

    for (int k0 = 0; k0 < DIM; k0 += 64) {
#pragma unroll
        for (int i = 0; i < 4; ++i) {
            int rr = srow + i * 8;
            int col = scol ^ ((rr & 7) << 3);
            int rg = bm + rr; rg = rg < M ? rg : M - 1;
            GLOAD_LDS16(Xb + (size_t)rg * DIM + k0 + col, &As[(w * 32 + i * 8) * 64]);
        }
#pragma unroll
        for (int i = 0; i < 4; ++i) {
            int rr = srow + i * 8;
            int col = scol ^ ((rr & 7) << 3);
            GLOAD_LDS16(Wt + (size_t)(bn + rr) * DIM + k0 + col, &Bs[(w * 32 + i * 8) * 64]);
        }
        __syncthreads();

#pragma unroll
        for (int kk = 0; kk < 2; ++kk) {
            bf16x8 af[4], bfr[4];
            int ke = kk * 32 + (lane >> 4) * 8;
#pragma unroll
            for (int mi = 0; mi < 4; ++mi) {
                int rr = wr * 64 + mi * 16 + (lane & 15);
                af[mi] = *(const bf16x8*)&As[rr * 64 + (ke ^ ((rr & 7) << 3))];
            }
#pragma unroll
            for (int ni = 0; ni < 4; ++ni) {
                int rr = wc * 64 + ni * 16 + (lane & 15);
                bfr[ni] = *(const bf16x8*)&Bs[rr * 64 + (ke ^ ((rr & 7) << 3))];
            }
#pragma unroll
            for (int mi = 0; mi < 4; ++mi)
#pragma unroll
                for (int ni = 0; ni < 4; ++ni)
                    acc[mi][ni] = __builtin_amdgcn_mfma_f32_16x16x32_bf16(
                        af[mi], bfr[ni], acc[mi][ni], 0, 0, 0);
        }
        __syncthreads();
    }

    __hip_bfloat16* C = (bn < DIM) ? C1 : C2;
    int cb = (bn < DIM) ? bn : bn - DIM;
#pragma unroll
    for (int mi = 0; mi < 4; ++mi) {
#pragma unroll
        for (int j = 0; j < 4; ++j) {
            int row = bm + wr * 64 + mi * 16 + (lane >> 4) * 4 + j;
            if (row < M) {
#pragma unroll
                for (int ni = 0; ni < 4; ++ni) {
                    int col = cb + wc * 64 + ni * 16 + (lane & 15);
                    C[(size_t)row * DIM + col] = __float2bfloat16(acc[mi][ni][j]);
                }
            }
        }
    }
}

// ---------------------------------------------------------------------------
// Per-node GAT: round-3 loop structure (48 VGPR, no spill) + defer-max (T13).
// One wave per dst node, online softmax, single gather pass.
// ---------------------------------------------------------------------------
__device__ __forceinline__ void load12(const unsigned short* __restrict__ p, float* v) {
    ushort4 a = *reinterpret_cast<const ushort4*>(p);
    ushort4 b = *reinterpret_cast<const ushort4*>(p + 4);
    ushort4 c = *reinterpret_cast<const ushort4*>(p + 8);
    v[0] = bf2f(a.x); v[1] = bf2f(a.y); v[2] = bf2f(a.z); v[3] = bf2f(a.w);
    v[4] = bf2f(b.x); v[5] = bf2f(b.y); v[6] = bf2f(b.z); v[7] = bf2f(b.w);
    v[8] = bf2f(c.x); v[9] = bf2f(c.y); v[10] = bf2f(c.z); v[11] = bf2f(c.w);
}

template <int H>
__global__ __launch_bounds__(256) void gat_node_kernel(
    const unsigned short* __restrict__ fs, const unsigned short* __restrict__ fd,
    const int* __restrict__ row_start, const int* __restrict__ csr_src,
    const float* __restrict__ attn, const float* __restrict__ resid,
    const float* __restrict__ ln_w, const float* __restrict__ ln_b,
    float* __restrict__ outf, __hip_bfloat16* __restrict__ outb, int n_nodes) {
    constexpr int G = 64 / H;
    int wave = threadIdx.x >> 6;
    int lane = threadIdx.x & 63;
    int node = blockIdx.x * 4 + wave;
    if (node >= n_nodes) return;
    int d0 = lane * 12;

    float fdv[12], av[12], agg[12];
    load12(fd + (size_t)node * DIM + d0, fdv);
    {
        const float4* p = reinterpret_cast<const float4*>(attn + d0);
        float4 q0 = p[0], q1 = p[1], q2 = p[2];
        av[0] = q0.x; av[1] = q0.y; av[2] = q0.z; av[3] = q0.w;
        av[4] = q1.x; av[5] = q1.y; av[6] = q1.z; av[7] = q1.w;
        av[8] = q2.x; av[9] = q2.y; av[10] = q2.z; av[11] = q2.w;
    }
#pragma unroll
    for (int j = 0; j < 12; ++j) agg[j] = 0.f;

    int p0 = row_start[node], p1 = row_start[node + 1];
    float m = -INFINITY;
    float denom = 0.f;

    int sNext = (p0 < p1) ? csr_src[p0] : 0;
    for (int p = p0; p < p1; ++p) {
        int s = sNext;
        sNext = (p + 1 < p1) ? csr_src[p + 1] : 0;
        float fv[12];
        load12(fs + (size_t)s * DIM + d0, fv);
        float t = 0.f;
#pragma unroll
        for (int j = 0; j < 12; ++j) {
            float u = fv[j] + fdv[j];
            u = fmaxf(u, 0.2f * u);
            t = fmaf(u, av[j], t);
        }
#pragma unroll
        for (int off = 1; off < G; off <<= 1) t += __shfl_xor(t, off, 64);
        // defer-max online softmax (T13, THR=8): common path skips rescale
        if (__builtin_expect(!__all(t <= m + 8.f), 0)) {
            float mn = fmaxf(m, t);
            float c  = __expf(m - mn);
            float ex = __expf(t - mn);
            denom = denom * c + ex;
#pragma unroll
            for (int j = 0; j < 12; ++j) agg[j] = fmaf(agg[j], c, ex * fv[j]);
            m = mn;
        } else {
            float ex = __expf(t - m);
            denom += ex;
#pragma unroll
            for (int j = 0; j < 12; ++j) agg[j] = fmaf(ex, fv[j], agg[j]);
        }
    }

    float inv = (denom > 0.f) ? 1.0f / denom : 0.f;
    float vals[12];
#pragma unroll
    for (int j = 0; j < 12; ++j) {
        float v = agg[j] * inv;
        vals[j] = (v > 0.f) ? v : expm1f(v);
    }
    if (resid != nullptr) {
        const float4* p = reinterpret_cast<const float4*>(resid + (size_t)node * DIM + d0);
        float4 q0 = p[0], q1 = p[1], q2 = p[2];
        vals[0] += q0.x; vals[1] += q0.y; vals[2] += q0.z; vals[3] += q0.w;
        vals[4] += q1.x; vals[5] += q1.y; vals[6] += q1.z; vals[7] += q1.w;
        vals[8] += q2.x; vals[9] += q2.y; vals[10] += q2.z; vals[11] += q2.w;
    }
    float s1 = 0.f;
#pragma unroll
    for (int j = 0; j < 12; ++j) s1 += vals[j];
#pragma unroll
    for (int off = 1; off < 64; off <<= 1) s1 += __shfl_xor(s1, off, 64);
    float mu = s1 * (1.0f / DIM);
    float s2 = 0.f;
#pragma unroll
    for (int j = 0; j < 12; ++j) {
        float dlt = vals[j] - mu;
        s2 = fmaf(dlt, dlt, s2);
    }
#pragma unroll
    for (int off = 1; off < 64; off <<= 1) s2 += __shfl_xor(s2, off, 64);
    float rs = rsqrtf(s2 * (1.0f / DIM) + 1e-5f);

    float wv[12], bv[12];
    {
        const float4* p = reinterpret_cast<const float4*>(ln_w + d0);
        float4 q0 = p[0], q1 = p[1], q2 = p[2];
        wv[0] = q0.x; wv[1] = q0.y; wv[2] = q0.z; wv[3] = q0.w;
        wv[4] = q1.x; wv[5] = q1.y; wv[6] = q1.z; wv[7] = q1.w;
        wv[8] = q2.x; wv[9] = q2.y; wv[10] = q2.z; wv[11] = q2.w;
        const float4* pb = reinterpret_cast<const float4*>(ln_b + d0);
        float4 r0 = pb[0], r1 = pb[1], r2 = pb[2];
        bv[0] = r0.x; bv[1] = r0.y; bv[2] = r0.z; bv[3] = r0.w;
        bv[4] = r1.x; bv[5] = r1.y; bv[6] = r1.z; bv[7] = r1.w;
        bv[8] = r2.x; bv[9] = r2.y; bv[10] = r2.z; bv[11] = r2.w;
    }
    float o[12];
#pragma unroll
    for (int j = 0; j < 12; ++j)
        o[j] = (vals[j] - mu) * rs * wv[j] + bv[j];

    if (outf != nullptr) {
        float* op = outf + (size_t)node * DIM + d0;
#pragma unroll
        for (int qq = 0; qq < 3; ++qq) {
            float4 t4 = make_float4(o[qq * 4 + 0], o[qq * 4 + 1], o[qq * 4 + 2], o[qq * 4 + 3]);
            *reinterpret_cast<float4*>(op + qq * 4) = t4;
        }
    }
    if (outb != nullptr) {
        __hip_bfloat16 hb[12];
#pragma unroll
        for (int j = 0; j < 12; ++j) hb[j] = __float2bfloat16(o[j]);
        unsigned short* op = (unsigned short*)outb + (size_t)node * DIM + d0;
#pragma unroll
        for (int qq = 0; qq < 3; ++qq)
            *reinterpret_cast<ushort4*>(op + qq * 4) =
                *reinterpret_cast<ushort4*>(&hb[qq * 4]);
    }
}

// ---------------------------------------------------------------------------
extern "C" void kernel_launch(void* const* d_in, const int* in_sizes, int n_in,
                              void* d_out, int out_size, void* d_ws, size_t ws_size,
                              hipStream_t stream) {
    const float* x     = (const float*)d_in[0];
    const int*   src   = (const int*)d_in[1];
    const int*   dst   = (const int*)d_in[2];
    const float* W1s   = (const float*)d_in[3];
    const float* b1s   = (const float*)d_in[4];
    const float* W1d   = (const float*)d_in[5];
    const float* b1d   = (const float*)d_in[6];
    const float* attn1 = (const float*)d_in[7];
    const float* ln1w  = (const float*)d_in[8];
    const float* ln1b  = (const float*)d_in[9];
    const float* Wos   = (const float*)d_in[10];
    const float* bos   = (const float*)d_in[11];
    const float* Wod   = (const float*)d_in[12];
    const float* bod   = (const float*)d_in[13];
    const float* attno = (const float*)d_in[14];
    const float* lnow  = (const float*)d_in[15];
    const float* lnob  = (const float*)d_in[16];
    float* out = (float*)d_out;

    const int N = in_sizes[0] / DIM;   // 20000
    const int E = in_sizes[1];         // 320000

    __hip_bfloat16* fsb = (__hip_bfloat16*)d_ws;
    __hip_bfloat16* fdb = fsb + (size_t)N * DIM;
    __hip_bfloat16* Xb  = fdb + (size_t)N * DIM;
    __hip_bfloat16* W1t = Xb + (size_t)N * DIM;
    __hip_bfloat16* Wot = W1t + (size_t)2 * DIM * DIM;
    int* csr_src   = (int*)(Wot + (size_t)2 * DIM * DIM);
    int* row_start = csr_src + E;
    int* cursor    = row_start + (N + 1);
    int* deg       = cursor + N;

    // --- CSR by dst (shared by both layers)
    hipMemsetAsync(deg, 0, (size_t)N * sizeof(int), stream);
    hist_kernel<<<(E + 255) / 256, 256, 0, stream>>>(dst, deg, E);
    scan_kernel<<<1, 1024, 0, stream>>>(deg, row_start, cursor, N);
    scatter_kernel<<<(E + 255) / 256, 256, 0, stream>>>(src, dst, cursor, csr_src, E);

    // --- weight transposes (f32 -> bf16, [K][N] -> [N][K])
    dim3 tg(DIM / 32, DIM / 32);
    transpose_bf16_kernel<<<tg, 256, 0, stream>>>(W1s, W1t, DIM, DIM);
    transpose_bf16_kernel<<<tg, 256, 0, stream>>>(W1d, W1t + (size_t)DIM * DIM, DIM, DIM);
    transpose_bf16_kernel<<<tg, 256, 0, stream>>>(Wos, Wot, DIM, DIM);
    transpose_bf16_kernel<<<tg, 256, 0, stream>>>(Wod, Wot + (size_t)DIM * DIM, DIM, DIM);

    const int n8 = N * DIM / 8;
    const int mt = (N + 127) / 128;
    const int nwg = mt * 12;  // 1D swizzled grid

    // --- layer 1: GEMM -> gat (writes bf16 h straight into Xb for layer 2)
    conv_bf16_kernel<<<(n8 + 255) / 256, 256, 0, stream>>>(x, Xb, n8);
    gemm_mfma_dual_kernel<<<nwg, 256, 0, stream>>>(
        (const bf16_t*)Xb, (const bf16_t*)W1t, b1s, b1d, fsb, fdb, N);
    gat_node_kernel<8><<<(N + 3) / 4, 256, 0, stream>>>(
        (const unsigned short*)fsb, (const unsigned short*)fdb, row_start, csr_src,
        attn1, x, ln1w, ln1b, nullptr, Xb, N);

    // --- layer 2: GEMM -> gat -> final f32 out
    gemm_mfma_dual_kernel<<<nwg, 256, 0, stream>>>(
        (const bf16_t*)Xb, (const bf16_t*)Wot, bos, bod, fsb, fdb, N);
    gat_node_kernel<1><<<(N + 3) / 4, 256, 0, stream>>>(
        (const unsigned short*)fsb, (const unsigned short*)fdb, row_start, csr_src,
        attno, nullptr, lnow, lnob, out, nullptr, N);
}

// Round 6
// 437.270 us; speedup vs baseline: 1.4550x; 1.0322x over previous
//
#include <hip/hip_runtime.h>
#include <hip/hip_bf16.h>
#include <math.h>

#define DIM 768

typedef __bf16 bf16_t;
typedef __attribute__((ext_vector_type(8))) __bf16 bf16x8;
typedef __attribute__((ext_vector_type(4))) float f32x4;

#define GLOAD_LDS16(g, l)                                                  \
    __builtin_amdgcn_global_load_lds(                                      \
        (const __attribute__((address_space(1))) void*)(g),                \
        (__attribute__((address_space(3))) void*)(l), 16, 0, 0)

__device__ __forceinline__ float bf2f(unsigned short u) {
    union { unsigned int i; float f; } x;
    x.i = ((unsigned int)u) << 16;
    return x.f;
}

// ---------------------------------------------------------------------------
// DPP-based group sum: VALU-only within 16 lanes (quad_perm xor1/xor2,
// half-mirror, mirror); cross-row via shfl. Valid for sum-reductions because
// after xor1+xor2 each quad is uniform, so mirror stages pair quads/octs.
// ---------------------------------------------------------------------------
template <int CTRL>
__device__ __forceinline__ float dpp_add(float v) {
    int s = __builtin_amdgcn_update_dpp(0, __float_as_int(v), CTRL, 0xF, 0xF, true);
    return v + __int_as_float(s);
}

template <int G>
__device__ __forceinline__ float group_sum(float t) {
    t = dpp_add<0xB1>(t);                         // quad_perm [1,0,3,2] : xor1
    t = dpp_add<0x4E>(t);                         // quad_perm [2,3,0,1] : xor2
    t = dpp_add<0x141>(t);                        // row_half_mirror: 8-group
    if constexpr (G >= 16) t = dpp_add<0x140>(t); // row_mirror: 16-group
    if constexpr (G >= 32) t += __shfl_xor(t, 16, 64);
    if constexpr (G >= 64) t += __shfl_xor(t, 32, 64);
    return t;
}

// ---------------------------------------------------------------------------
// CSR build
// ---------------------------------------------------------------------------
__global__ __launch_bounds__(256) void hist_kernel(const int* __restrict__ dst,
                                                   int* __restrict__ deg, int E) {
    int e = blockIdx.x * 256 + threadIdx.x;
    if (e < E) atomicAdd(&deg[dst[e]], 1);
}

__global__ __launch_bounds__(1024) void scan_kernel(const int* __restrict__ deg,
                                                    int* __restrict__ row_start,
                                                    int* __restrict__ cursor, int n) {
    __shared__ int sh[1024];
    __shared__ int carry_sh;
    int tid = threadIdx.x;
    if (tid == 0) carry_sh = 0;
    __syncthreads();
    for (int base = 0; base < n; base += 1024) {
        int i = base + tid;
        int v = (i < n) ? deg[i] : 0;
        sh[tid] = v;
        __syncthreads();
        for (int off = 1; off < 1024; off <<= 1) {
            int t = (tid >= off) ? sh[tid - off] : 0;
            __syncthreads();
            sh[tid] += t;
            __syncthreads();
        }
        int incl = sh[tid];
        int carry = carry_sh;
        int excl = carry + incl - v;
        if (i < n) { row_start[i] = excl; cursor[i] = excl; }
        __syncthreads();
        if (tid == 1023) carry_sh = carry + incl;
        __syncthreads();
    }
    if (tid == 0) row_start[n] = carry_sh;
}

__global__ __launch_bounds__(256) void scatter_kernel(const int* __restrict__ src,
                                                      const int* __restrict__ dst,
                                                      int* __restrict__ cursor,
                                                      int* __restrict__ csr_src, int E) {
    int e = blockIdx.x * 256 + threadIdx.x;
    if (e < E) {
        int p = atomicAdd(&cursor[dst[e]], 1);
        csr_src[p] = src[e];
    }
}

// ---------------------------------------------------------------------------
// fp32 -> bf16 elementwise convert (8 elems/thread)
// ---------------------------------------------------------------------------
__global__ __launch_bounds__(256) void conv_bf16_kernel(const float* __restrict__ in,
                                                        __hip_bfloat16* __restrict__ out,
                                                        int n8) {
    int i = blockIdx.x * 256 + threadIdx.x;
    if (i >= n8) return;
    const float4* p = reinterpret_cast<const float4*>(in + (size_t)i * 8);
    float4 a = p[0], b = p[1];
    __hip_bfloat16 v[8];
    v[0] = __float2bfloat16(a.x); v[1] = __float2bfloat16(a.y);
    v[2] = __float2bfloat16(a.z); v[3] = __float2bfloat16(a.w);
    v[4] = __float2bfloat16(b.x); v[5] = __float2bfloat16(b.y);
    v[6] = __float2bfloat16(b.z); v[7] = __float2bfloat16(b.w);
    *reinterpret_cast<uint4*>(out + (size_t)i * 8) = *reinterpret_cast<uint4*>(v);
}

// ---------------------------------------------------------------------------
// W [K][Nc] f32  ->  Wt [Nc][K] bf16  (tiled transpose)
// ---------------------------------------------------------------------------
__global__ __launch_bounds__(256) void transpose_bf16_kernel(const float* __restrict__ W,
                                                             __hip_bfloat16* __restrict__ Wt,
                                                             int K, int Nc) {
    __shared__ float tile[32][33];
    int bk = blockIdx.x * 32, bn = blockIdx.y * 32;
    int tx = threadIdx.x & 31, ty = threadIdx.x >> 5;  // 32 x 8
#pragma unroll
    for (int r = ty; r < 32; r += 8)
        tile[r][tx] = W[(size_t)(bk + r) * Nc + bn + tx];
    __syncthreads();
#pragma unroll
    for (int r = ty; r < 32; r += 8)
        Wt[(size_t)(bn + r) * K + bk + tx] = __float2bfloat16(tile[tx][r]);
}

// ---------------------------------------------------------------------------
// Dual bf16 MFMA GEMM, 1D grid with bijective XCD-chunk swizzle (T1/m204)
// ---------------------------------------------------------------------------
__global__ __launch_bounds__(256) void gemm_mfma_dual_kernel(
    const bf16_t* __restrict__ Xb,   // [M][768]
    const bf16_t* __restrict__ Wt,   // [1536][768]
    const float* __restrict__ b1, const float* __restrict__ b2,
    __hip_bfloat16* __restrict__ C1, __hip_bfloat16* __restrict__ C2, int M) {
    __shared__ __align__(16) bf16_t As[128 * 64];
    __shared__ __align__(16) bf16_t Bs[128 * 64];

    const int nwg = gridDim.x;
    const int o = blockIdx.x;
    const int q = nwg >> 3, r = nwg & 7;
    const int xcd = o & 7, jj = o >> 3;
    const int lin = (xcd < r ? xcd * (q + 1) : r * (q + 1) + (xcd - r) * q) + jj;
    const int bn = (lin % 12) * 128;
    const int bm = (lin / 12) * 128;

    const int tid = threadIdx.x;
    const int lane = tid & 63;
    const int w = tid >> 6;
    const int wr = w >> 1, wc = w & 1;

    f32x4 acc[4][4];
    {
        const float* bp = (bn < DIM) ? b1 : b2;
        int cb = (bn < DIM) ? bn : bn - DIM;
#pragma unroll
        for (int ni = 0; ni < 4; ++ni) {
            float bv = bp[cb + wc * 64 + ni * 16 + (lane & 15)];
#pragma unroll
            for (int mi = 0; mi < 4; ++mi) acc[mi][ni] = f32x4{bv, bv, bv, bv};
        }
    }

    const int srow = w * 32 + (lane >> 3);
    const int scol = (lane & 7) * 8;

    for (int k0 = 0; k0 < DIM; k0 += 64) {
#pragma unroll
        for (int i = 0; i < 4; ++i) {
            int rr = srow + i * 8;
            int col = scol ^ ((rr & 7) << 3);
            int rg = bm + rr; rg = rg < M ? rg : M - 1;
            GLOAD_LDS16(Xb + (size_t)rg * DIM + k0 + col, &As[(w * 32 + i * 8) * 64]);
        }
#pragma unroll
        for (int i = 0; i < 4; ++i) {
            int rr = srow + i * 8;
            int col = scol ^ ((rr & 7) << 3);
            GLOAD_LDS16(Wt + (size_t)(bn + rr) * DIM + k0 + col, &Bs[(w * 32 + i * 8) * 64]);
        }
        __syncthreads();

#pragma unroll
        for (int kk = 0; kk < 2; ++kk) {
            bf16x8 af[4], bfr[4];
            int ke = kk * 32 + (lane >> 4) * 8;
#pragma unroll
            for (int mi = 0; mi < 4; ++mi) {
                int rr = wr * 64 + mi * 16 + (lane & 15);
                af[mi] = *(const bf16x8*)&As[rr * 64 + (ke ^ ((rr & 7) << 3))];
            }
#pragma unroll
            for (int ni = 0; ni < 4; ++ni) {
                int rr = wc * 64 + ni * 16 + (lane & 15);
                bfr[ni] = *(const bf16x8*)&Bs[rr * 64 + (ke ^ ((rr & 7) << 3))];
            }
#pragma unroll
            for (int mi = 0; mi < 4; ++mi)
#pragma unroll
                for (int ni = 0; ni < 4; ++ni)
                    acc[mi][ni] = __builtin_amdgcn_mfma_f32_16x16x32_bf16(
                        af[mi], bfr[ni], acc[mi][ni], 0, 0, 0);
        }
        __syncthreads();
    }

    __hip_bfloat16* C = (bn < DIM) ? C1 : C2;
    int cb = (bn < DIM) ? bn : bn - DIM;
#pragma unroll
    for (int mi = 0; mi < 4; ++mi) {
#pragma unroll
        for (int j = 0; j < 4; ++j) {
            int row = bm + wr * 64 + mi * 16 + (lane >> 4) * 4 + j;
            if (row < M) {
#pragma unroll
                for (int ni = 0; ni < 4; ++ni) {
                    int col = cb + wc * 64 + ni * 16 + (lane & 15);
                    C[(size_t)row * DIM + col] = __float2bfloat16(acc[mi][ni][j]);
                }
            }
        }
    }
}

// ---------------------------------------------------------------------------
// Per-node GAT: online softmax + defer-max + DPP group reduce + 2-deep edge
// prefetch (NO occupancy cap -- round-4 spill was caused by the cap).
// ---------------------------------------------------------------------------
__device__ __forceinline__ void load12(const unsigned short* __restrict__ p, float* v) {
    ushort4 a = *reinterpret_cast<const ushort4*>(p);
    ushort4 b = *reinterpret_cast<const ushort4*>(p + 4);
    ushort4 c = *reinterpret_cast<const ushort4*>(p + 8);
    v[0] = bf2f(a.x); v[1] = bf2f(a.y); v[2] = bf2f(a.z); v[3] = bf2f(a.w);
    v[4] = bf2f(b.x); v[5] = bf2f(b.y); v[6] = bf2f(b.z); v[7] = bf2f(b.w);
    v[8] = bf2f(c.x); v[9] = bf2f(c.y); v[10] = bf2f(c.z); v[11] = bf2f(c.w);
}

// one edge: logit -> DPP group reduce -> defer-max online softmax update
#define PROCESS(FV)                                                         \
    do {                                                                    \
        float t = 0.f;                                                      \
        _Pragma("unroll") for (int j = 0; j < 12; ++j) {                    \
            float u = FV[j] + fdv[j];                                       \
            u = fmaxf(u, 0.2f * u);                                         \
            t = fmaf(u, av[j], t);                                          \
        }                                                                   \
        t = group_sum<G>(t);                                                \
        if (__builtin_expect(!__all(t <= m + 8.f), 0)) {                    \
            float mn = fmaxf(m, t);                                         \
            float c = __expf(m - mn);                                       \
            float ex = __expf(t - mn);                                      \
            denom = denom * c + ex;                                         \
            _Pragma("unroll") for (int j = 0; j < 12; ++j)                  \
                agg[j] = fmaf(agg[j], c, ex * FV[j]);                       \
            m = mn;                                                         \
        } else {                                                            \
            float ex = __expf(t - m);                                       \
            denom += ex;                                                    \
            _Pragma("unroll") for (int j = 0; j < 12; ++j)                  \
                agg[j] = fmaf(ex, FV[j], agg[j]);                           \
        }                                                                   \
    } while (0)

template <int H>
__global__ __launch_bounds__(256) void gat_node_kernel(
    const unsigned short* __restrict__ fs, const unsigned short* __restrict__ fd,
    const int* __restrict__ row_start, const int* __restrict__ csr_src,
    const float* __restrict__ attn, const float* __restrict__ resid,
    const float* __restrict__ ln_w, const float* __restrict__ ln_b,
    float* __restrict__ outf, __hip_bfloat16* __restrict__ outb, int n_nodes) {
    constexpr int G = 64 / H;
    int wave = threadIdx.x >> 6;
    int lane = threadIdx.x & 63;
    int node = blockIdx.x * 4 + wave;
    if (node >= n_nodes) return;
    int d0 = lane * 12;

    float fdv[12], av[12], agg[12];
    load12(fd + (size_t)node * DIM + d0, fdv);
    {
        const float4* p = reinterpret_cast<const float4*>(attn + d0);
        float4 q0 = p[0], q1 = p[1], q2 = p[2];
        av[0] = q0.x; av[1] = q0.y; av[2] = q0.z; av[3] = q0.w;
        av[4] = q1.x; av[5] = q1.y; av[6] = q1.z; av[7] = q1.w;
        av[8] = q2.x; av[9] = q2.y; av[10] = q2.z; av[11] = q2.w;
    }
#pragma unroll
    for (int j = 0; j < 12; ++j) agg[j] = 0.f;

    int p0 = row_start[node], p1 = row_start[node + 1];
    int np = p1 - p0;
    float m = -INFINITY;
    float denom = 0.f;

    const unsigned short* fsl = fs + d0;
    const int* ip = csr_src + p0;

    float fvA[12], fvB[12];
    if (np > 0) load12(fsl + (size_t)ip[0] * DIM, fvA);
    if (np > 1) load12(fsl + (size_t)ip[1] * DIM, fvB);

    int i = 0;
    for (; i + 2 <= np; i += 2) {
        PROCESS(fvA);
        if (i + 2 < np) load12(fsl + (size_t)ip[i + 2] * DIM, fvA);
        PROCESS(fvB);
        if (i + 3 < np) load12(fsl + (size_t)ip[i + 3] * DIM, fvB);
    }
    if (i < np) PROCESS(fvA);

    float inv = (denom > 0.f) ? 1.0f / denom : 0.f;
    float vals[12];
#pragma unroll
    for (int j = 0; j < 12; ++j) {
        float v = agg[j] * inv;
        vals[j] = (v > 0.f) ? v : expm1f(v);
    }
    if (resid != nullptr) {
        const float4* p = reinterpret_cast<const float4*>(resid + (size_t)node * DIM + d0);
        float4 q0 = p[0], q1 = p[1], q2 = p[2];
        vals[0] += q0.x; vals[1] += q0.y; vals[2] += q0.z; vals[3] += q0.w;
        vals[4] += q1.x; vals[5] += q1.y; vals[6] += q1.z; vals[7] += q1.w;
        vals[8] += q2.x; vals[9] += q2.y; vals[10] += q2.z; vals[11] += q2.w;
    }
    float s1 = 0.f;
#pragma unroll
    for (int j = 0; j < 12; ++j) s1 += vals[j];
    s1 = group_sum<64>(s1);
    float mu = s1 * (1.0f / DIM);
    float s2 = 0.f;
#pragma unroll
    for (int j = 0; j < 12; ++j) {
        float dlt = vals[j] - mu;
        s2 = fmaf(dlt, dlt, s2);
    }
    s2 = group_sum<64>(s2);
    float rs = rsqrtf(s2 * (1.0f / DIM) + 1e-5f);

    float wv[12], bv[12];
    {
        const float4* p = reinterpret_cast<const float4*>(ln_w + d0);
        float4 q0 = p[0], q1 = p[1], q2 = p[2];
        wv[0] = q0.x; wv[1] = q0.y; wv[2] = q0.z; wv[3] = q0.w;
        wv[4] = q1.x; wv[5] = q1.y; wv[6] = q1.z; wv[7] = q1.w;
        wv[8] = q2.x; wv[9] = q2.y; wv[10] = q2.z; wv[11] = q2.w;
        const float4* pb = reinterpret_cast<const float4*>(ln_b + d0);
        float4 r0 = pb[0], r1 = pb[1], r2 = pb[2];
        bv[0] = r0.x; bv[1] = r0.y; bv[2] = r0.z; bv[3] = r0.w;
        bv[4] = r1.x; bv[5] = r1.y; bv[6] = r1.z; bv[7] = r1.w;
        bv[8] = r2.x; bv[9] = r2.y; bv[10] = r2.z; bv[11] = r2.w;
    }
    float o[12];
#pragma unroll
    for (int j = 0; j < 12; ++j)
        o[j] = (vals[j] - mu) * rs * wv[j] + bv[j];

    if (outf != nullptr) {
        float* op = outf + (size_t)node * DIM + d0;
#pragma unroll
        for (int qq = 0; qq < 3; ++qq) {
            float4 t4 = make_float4(o[qq * 4 + 0], o[qq * 4 + 1], o[qq * 4 + 2], o[qq * 4 + 3]);
            *reinterpret_cast<float4*>(op + qq * 4) = t4;
        }
    }
    if (outb != nullptr) {
        __hip_bfloat16 hb[12];
#pragma unroll
        for (int j = 0; j < 12; ++j) hb[j] = __float2bfloat16(o[j]);
        unsigned short* op = (unsigned short*)outb + (size_t)node * DIM + d0;
#pragma unroll
        for (int qq = 0; qq < 3; ++qq)
            *reinterpret_cast<ushort4*>(op + qq * 4) =
                *reinterpret_cast<ushort4*>(&hb[qq * 4]);
    }
}

// ---------------------------------------------------------------------------
extern "C" void kernel_launch(void* const* d_in, const int* in_sizes, int n_in,
                              void* d_out, int out_size, void* d_ws, size_t ws_size,
                              hipStream_t stream) {
    const float* x     = (const float*)d_in[0];
    const int*   src   = (const int*)d_in[1];
    const int*   dst   = (const int*)d_in[2];
    const float* W1s   = (const float*)d_in[3];
    const float* b1s   = (const float*)d_in[4];
    const float* W1d   = (const float*)d_in[5];
    const float* b1d   = (const float*)d_in[6];
    const float* attn1 = (const float*)d_in[7];
    const float* ln1w  = (const float*)d_in[8];
    const float* ln1b  = (const float*)d_in[9];
    const float* Wos   = (const float*)d_in[10];
    const float* bos   = (const float*)d_in[11];
    const float* Wod   = (const float*)d_in[12];
    const float* bod   = (const float*)d_in[13];
    const float* attno = (const float*)d_in[14];
    const float* lnow  = (const float*)d_in[15];
    const float* lnob  = (const float*)d_in[16];
    float* out = (float*)d_out;

    const int N = in_sizes[0] / DIM;   // 20000
    const int E = in_sizes[1];         // 320000

    __hip_bfloat16* fsb = (__hip_bfloat16*)d_ws;
    __hip_bfloat16* fdb = fsb + (size_t)N * DIM;
    __hip_bfloat16* Xb  = fdb + (size_t)N * DIM;
    __hip_bfloat16* W1t = Xb + (size_t)N * DIM;
    __hip_bfloat16* Wot = W1t + (size_t)2 * DIM * DIM;
    int* csr_src   = (int*)(Wot + (size_t)2 * DIM * DIM);
    int* row_start = csr_src + E;
    int* cursor    = row_start + (N + 1);
    int* deg       = cursor + N;

    // --- CSR by dst (shared by both layers)
    hipMemsetAsync(deg, 0, (size_t)N * sizeof(int), stream);
    hist_kernel<<<(E + 255) / 256, 256, 0, stream>>>(dst, deg, E);
    scan_kernel<<<1, 1024, 0, stream>>>(deg, row_start, cursor, N);
    scatter_kernel<<<(E + 255) / 256, 256, 0, stream>>>(src, dst, cursor, csr_src, E);

    // --- weight transposes (f32 -> bf16, [K][N] -> [N][K])
    dim3 tg(DIM / 32, DIM / 32);
    transpose_bf16_kernel<<<tg, 256, 0, stream>>>(W1s, W1t, DIM, DIM);
    transpose_bf16_kernel<<<tg, 256, 0, stream>>>(W1d, W1t + (size_t)DIM * DIM, DIM, DIM);
    transpose_bf16_kernel<<<tg, 256, 0, stream>>>(Wos, Wot, DIM, DIM);
    transpose_bf16_kernel<<<tg, 256, 0, stream>>>(Wod, Wot + (size_t)DIM * DIM, DIM, DIM);

    const int n8 = N * DIM / 8;
    const int mt = (N + 127) / 128;
    const int nwg = mt * 12;  // 1D swizzled grid

    // --- layer 1: GEMM -> gat (writes bf16 h straight into Xb for layer 2)
    conv_bf16_kernel<<<(n8 + 255) / 256, 256, 0, stream>>>(x, Xb, n8);
    gemm_mfma_dual_kernel<<<nwg, 256, 0, stream>>>(
        (const bf16_t*)Xb, (const bf16_t*)W1t, b1s, b1d, fsb, fdb, N);
    gat_node_kernel<8><<<(N + 3) / 4, 256, 0, stream>>>(
        (const unsigned short*)fsb, (const unsigned short*)fdb, row_start, csr_src,
        attn1, x, ln1w, ln1b, nullptr, Xb, N);

    // --- layer 2: GEMM -> gat -> final f32 out
    gemm_mfma_dual_kernel<<<nwg, 256, 0, stream>>>(
        (const bf16_t*)Xb, (const bf16_t*)Wot, bos, bod, fsb, fdb, N);
    gat_node_kernel<1><<<(N + 3) / 4, 256, 0, stream>>>(
        (const unsigned short*)fsb, (const unsigned short*)fdb, row_start, csr_src,
        attno, nullptr, lnow, lnob, out, nullptr, N);
}